// Round 4
// baseline (1210.036 us; speedup 1.0000x reference)
//
#include <hip/hip_runtime.h>

typedef unsigned int uint;
typedef unsigned short ushort;
typedef __attribute__((ext_vector_type(8))) short b16x8;
typedef __attribute__((ext_vector_type(4))) float f32x4;

// ws byte offsets
#define PHIUT_OFF 0u
#define SQLP_OFF  524288u
#define SMU_OFF   (524288u + 65536u)
#define WBUF_OFF  (524288u + 131072u)
#define KLSO_OFF  (524288u + 131072u + 1048576u)

__device__ __forceinline__ ushort f2bf(float x){
  union { float f; uint u; } v; v.f = x;
  uint r = v.u + 0x7fffu + ((v.u >> 16) & 1u);
  return (ushort)(r >> 16);
}
__device__ __forceinline__ float bflo(uint u){ union { uint uu; float f; } v; v.uu = u << 16; return v.f; }
__device__ __forceinline__ float bfhi(uint u){ union { uint uu; float f; } v; v.uu = u & 0xffff0000u; return v.f; }

// C = A_rows · B_rows^T (NT), 128x128x128, bf16 MFMA 16x16x32.
// wave wv owns tile-rows {2wv, 2wv+1} x all 8 tile-cols.
__device__ __forceinline__ void mfma128(const ushort (*A)[136], const ushort (*B)[136],
                                        f32x4 acc[2][8], int wv, int lane){
  const int lr = lane & 15, lk = lane >> 4;
  #pragma unroll
  for (int ti = 0; ti < 2; ++ti)
    #pragma unroll
    for (int tj = 0; tj < 8; ++tj)
      acc[ti][tj] = (f32x4){0.f, 0.f, 0.f, 0.f};
  #pragma unroll
  for (int kk = 0; kk < 4; ++kk){
    const int kof = kk * 32 + lk * 8;
    b16x8 a0 = *(const b16x8*)&A[(wv * 2 + 0) * 16 + lr][kof];
    b16x8 a1 = *(const b16x8*)&A[(wv * 2 + 1) * 16 + lr][kof];
    #pragma unroll
    for (int tj = 0; tj < 8; ++tj){
      b16x8 bf = *(const b16x8*)&B[tj * 16 + lr][kof];
      acc[0][tj] = __builtin_amdgcn_mfma_f32_16x16x32_bf16(a0, bf, acc[0][tj], 0, 0, 0);
      acc[1][tj] = __builtin_amdgcn_mfma_f32_16x16x32_bf16(a1, bf, acc[1][tj], 0, 0, 0);
    }
  }
}

// bf16 panel operand writeback into the dead upper-right corner of Bm.
// PA (= -Y = -L*d) at Bm rows [0..31], cols [68..131]; PB (= L) at rows [32..63].
__device__ __forceinline__ void wpab(float (*Bm)[132], const float* dvec, int k0, int r, const f32x4* y){
  #pragma unroll
  for (int q = 0; q < 4; ++q){
    f32x4 y0 = y[2 * q], y1 = y[2 * q + 1];
    f32x4 d0 = *(const f32x4*)&dvec[k0 + q * 8];
    f32x4 d1 = *(const f32x4*)&dvec[k0 + q * 8 + 4];
    f32x4 a0 = (f32x4){0.f,0.f,0.f,0.f} - y0 * d0;
    f32x4 a1 = (f32x4){0.f,0.f,0.f,0.f} - y1 * d1;
    uint4 ua, ub;
    ua.x = (uint)f2bf(a0[0]) | ((uint)f2bf(a0[1]) << 16);
    ua.y = (uint)f2bf(a0[2]) | ((uint)f2bf(a0[3]) << 16);
    ua.z = (uint)f2bf(a1[0]) | ((uint)f2bf(a1[1]) << 16);
    ua.w = (uint)f2bf(a1[2]) | ((uint)f2bf(a1[3]) << 16);
    ub.x = (uint)f2bf(y0[0]) | ((uint)f2bf(y0[1]) << 16);
    ub.y = (uint)f2bf(y0[2]) | ((uint)f2bf(y0[3]) << 16);
    ub.z = (uint)f2bf(y1[0]) | ((uint)f2bf(y1[1]) << 16);
    ub.w = (uint)f2bf(y1[2]) | ((uint)f2bf(y1[3]) << 16);
    int fidx = r * 16 + q * 4;
    *(uint4*)&Bm[fidx >> 6][68 + (fidx & 63)] = ua;
    *(uint4*)&Bm[32 + (fidx >> 6)][68 + (fidx & 63)] = ub;
  }
}

// ---------------- K0: prep (phiU^T bf16, exp(lp/2), exp(lp/2)*mu) ----------------
__global__ void k0_prep(const float* __restrict__ U, const float* __restrict__ mu,
                        const float* __restrict__ lp, ushort* __restrict__ phiUT,
                        float* __restrict__ sqlp, float* __restrict__ smu)
{
  __shared__ __align__(16) ushort T0[128][132];
  const int tid = threadIdx.x;
  const int bid = blockIdx.x;
  if (bid < 16){
    const float* Us = U + ((size_t)bid << 14);
    for (int e = tid * 4; e < 16384; e += 1024){
      f32x4 v = *(const f32x4*)&Us[e];
      int m = e >> 7, d = e & 127;
      uint p0 = (uint)f2bf(fmaxf(v[0], 0.f)) | ((uint)f2bf(fmaxf(v[1], 0.f)) << 16);
      uint p1 = (uint)f2bf(fmaxf(v[2], 0.f)) | ((uint)f2bf(fmaxf(v[3], 0.f)) << 16);
      uint2 pv; pv.x = p0; pv.y = p1;
      *(uint2*)&T0[m][d] = pv;
    }
    __syncthreads();
    ushort* op = phiUT + ((size_t)bid << 14);
    for (int e = tid; e < 16384; e += 256){
      int d = e >> 7, m2 = e & 127;
      op[e] = T0[m2][d];
    }
  } else {
    int idx = ((bid - 16) << 8) + tid;
    float l = lp[idx], m = mu[idx];
    float ex = expf(0.5f * l);
    sqlp[idx] = ex;
    smu[idx]  = ex * m;
  }
}

// ---------------- K2: per-(s,o) factorization ----------------
// Reversed space: B = J A J = Wt·Wt^T + I with Wt[d'] = sqrtLp ⊙ phiUT[127-d'].
// LDL: B = L~ D L~^T ; S = L~^{-1} (in place). Then:
//   logdet_prec = Σ log d_k ; tr(q_cov) = Σ_i ||S row i||²/d_i
//   p = S v~ ; qmu~ = S^T (p/d) ; w~ = qmu~ + S^T (eps~/√d) ; w[d] = w~[127-d]
__global__ __launch_bounds__(256, 2) void k2_factor(
    const ushort* __restrict__ phiUT, const float* __restrict__ sqlp,
    const float* __restrict__ smu, const float* __restrict__ eps,
    float* __restrict__ wout, float* __restrict__ klso)
{
  __shared__ __align__(16) float Bm[128][132];
  __shared__ __align__(16) float Tscr[4][2][16][16];
  __shared__ __align__(16) float svec[128];
  __shared__ __align__(16) float smuv[128];
  __shared__ __align__(16) float epsv[128];
  __shared__ __align__(16) float utlv[128];
  __shared__ __align__(16) float dvec[128];
  __shared__ __align__(16) float pvec[128];
  __shared__ __align__(16) float qmuv[128];
  __shared__ __align__(16) float wtv[128];
  float* trv = smuv;   // smuv dead after phase 3
  float* red = svec;   // svec dead after phase 6
  float* brow = svec;  // 32-float pivot-row broadcast buffer during LDL
  ushort (*Wt)[136] = (ushort (*)[136])&Bm[0][0];

  const int tid  = threadIdx.x;
  const int lane = tid & 63;
  const int wv   = tid >> 6;
  const int s    = blockIdx.x >> 7;
  const int o    = blockIdx.x & 127;

  // phase 1: vectors
  if (tid < 128){
    svec[tid] = sqlp[(o << 7) + tid];
    epsv[tid] = eps[(((size_t)s * 128 + o) << 7) + 127 - tid];
  } else {
    int t2 = tid - 128;
    smuv[t2] = smu[(o << 7) + t2];
  }
  __syncthreads();

  // phase 2: Wt fill (reversed rows, scaled, bf16)
  for (int e = tid * 8; e < 16384; e += 2048){
    int dp = e >> 7, m = e & 127;
    const ushort* srcp = phiUT + (((size_t)s) << 14) + ((size_t)(127 - dp) << 7) + m;
    uint4 raw = *(const uint4*)srcp;
    f32x4 c0 = *(f32x4*)&svec[m];
    f32x4 c1 = *(f32x4*)&svec[m + 4];
    uint o0 = (uint)f2bf(bflo(raw.x) * c0[0]) | ((uint)f2bf(bfhi(raw.x) * c0[1]) << 16);
    uint o1 = (uint)f2bf(bflo(raw.y) * c0[2]) | ((uint)f2bf(bfhi(raw.y) * c0[3]) << 16);
    uint o2 = (uint)f2bf(bflo(raw.z) * c1[0]) | ((uint)f2bf(bfhi(raw.z) * c1[1]) << 16);
    uint o3 = (uint)f2bf(bflo(raw.w) * c1[2]) | ((uint)f2bf(bfhi(raw.w) * c1[3]) << 16);
    uint4 ov; ov.x = o0; ov.y = o1; ov.z = o2; ov.w = o3;
    *(uint4*)&Wt[dp][m] = ov;
  }
  __syncthreads();

  // phase 3: v~ = Wt · (sqrtLp ⊙ mu)
  if (tid < 128){
    float acc3 = 0.f;
    for (int m = 0; m < 128; m += 8){
      uint4 raw = *(uint4*)&Wt[tid][m];
      f32x4 u0 = *(f32x4*)&smuv[m];
      f32x4 u1 = *(f32x4*)&smuv[m + 4];
      acc3 += bflo(raw.x) * u0[0] + bfhi(raw.x) * u0[1]
            + bflo(raw.y) * u0[2] + bfhi(raw.y) * u0[3]
            + bflo(raw.z) * u1[0] + bfhi(raw.z) * u1[1]
            + bflo(raw.w) * u1[2] + bfhi(raw.w) * u1[3];
    }
    utlv[tid] = acc3;
  }
  __syncthreads();

  // phase 4: MFMA Gram
  f32x4 acc[2][8];
  mfma128(Wt, Wt, acc, wv, lane);
  __syncthreads();  // Wt reads complete before overwrite

  // phase 5: Bm = Gram + I (full matrix)
  {
    const int lr = lane & 15, lk = lane >> 4;
    #pragma unroll
    for (int ti = 0; ti < 2; ++ti){
      #pragma unroll
      for (int tj = 0; tj < 8; ++tj){
        int c = tj * 16 + lr;
        #pragma unroll
        for (int q = 0; q < 4; ++q){
          int r = (wv * 2 + ti) * 16 + lk * 4 + q;
          float v = acc[ti][tj][q];
          if (r == c) v += 1.0f;
          Bm[r][c] = v;
        }
      }
    }
  }
  __syncthreads();

  // phase 6: blocked LDL, panel width 32; wave0 factors panel in registers,
  // all waves apply MFMA bf16 trailing update.
  // Trailing must maintain, besides the lower triangle, the super-diagonal
  // 16x16 band at EVERY future panel boundary (tiles (2k,2k+1) rel b0):
  // panel p' reads rows [32p',32p'+16) x cols [32p'+16,32p'+32) and needs
  // the accumulated Schur updates from all panels p < p' there.
  for (int p = 0; p < 4; ++p){
    const int k0 = p << 5;
    const int nrows = 128 - k0;
    if (wv == 0){
      const int r0 = k0 + lane, r1 = k0 + 64 + lane;
      const bool h0 = lane < nrows;
      const bool h1 = (64 + lane) < nrows;
      f32x4 ya[8], yb[8];
      #pragma unroll
      for (int j4 = 0; j4 < 8; ++j4){
        ya[j4] = h0 ? *(f32x4*)&Bm[r0][k0 + 4 * j4] : (f32x4){0.f,0.f,0.f,0.f};
        yb[j4] = h1 ? *(f32x4*)&Bm[r1][k0 + 4 * j4] : (f32x4){0.f,0.f,0.f,0.f};
      }
      #pragma unroll
      for (int t = 0; t < 32; ++t){
        const int t4 = t >> 2, tq = t & 3;
        if (lane == t){
          #pragma unroll
          for (int j4 = t4; j4 < 8; ++j4) *(f32x4*)&brow[4 * j4] = ya[j4];
        }
        __builtin_amdgcn_wave_barrier();
        f32x4 br[8];
        #pragma unroll
        for (int j4 = t4; j4 < 8; ++j4) br[j4] = *(f32x4*)&brow[4 * j4];
        __builtin_amdgcn_wave_barrier();
        float d = br[t4][tq];
        if (lane == t) dvec[k0 + t] = d;
        float rk = 1.0f / d;
        f32x4 bt = br[t4];
        bt[0] = 0.f;
        if (tq >= 1) bt[1] = 0.f;
        if (tq >= 2) bt[2] = 0.f;
        if (tq >= 3) bt[3] = 0.f;
        if (h0 && lane > t){
          float m0 = ya[t4][tq] * rk;
          ya[t4] = ya[t4] - m0 * bt;
          ya[t4][tq] = m0;
          #pragma unroll
          for (int j4 = t4 + 1; j4 < 8; ++j4) ya[j4] = ya[j4] - m0 * br[j4];
        }
        if (h1){
          float m1 = yb[t4][tq] * rk;
          yb[t4] = yb[t4] - m1 * bt;
          yb[t4][tq] = m1;
          #pragma unroll
          for (int j4 = t4 + 1; j4 < 8; ++j4) yb[j4] = yb[j4] - m1 * br[j4];
        }
      }
      __builtin_amdgcn_wave_barrier();
      // writeback: fp32 L (unit diag) to Bm lower; bf16 -Y / L for trailing rows
      if (h0){
        #pragma unroll
        for (int j4 = 0; j4 < 8; ++j4) *(f32x4*)&Bm[r0][k0 + 4 * j4] = ya[j4];
        if (lane < 32) Bm[r0][k0 + lane] = 1.0f;
      }
      if (h1){
        #pragma unroll
        for (int j4 = 0; j4 < 8; ++j4) *(f32x4*)&Bm[r1][k0 + 4 * j4] = yb[j4];
      }
      if (p < 3){
        if (h0 && lane >= 32) wpab(Bm, dvec, k0, r0, ya);
        if (h1)               wpab(Bm, dvec, k0, r1, yb);
      }
    }
    __syncthreads();
    if (p < 3){
      const int b0 = k0 + 32, n = 128 - b0, ntile = n >> 4;
      const int tiles = (ntile * (ntile + 1)) >> 1;
      // extras: super-diagonal tiles (2k, 2k+1) for every future panel boundary
      const int nextra = ntile >> 1;
      const int ntot = tiles + nextra;
      const int lr = lane & 15, lk = lane >> 4;
      for (int idx = wv; idx < ntot; idx += 4){
        int i0, j0;
        if (idx >= tiles){
          int k = idx - tiles;
          i0 = b0 + (k << 5); j0 = i0 + 16;
        } else {
          int ti = 0;
          while ((ti + 1) * (ti + 2) / 2 <= idx) ++ti;
          int tj = idx - ti * (ti + 1) / 2;
          i0 = b0 + (ti << 4); j0 = b0 + (tj << 4);
        }
        int crow = i0 + (lk << 2), ccol = j0 + lr;
        f32x4 c;
        #pragma unroll
        for (int q = 0; q < 4; ++q) c[q] = Bm[crow + q][ccol];
        int pia = (i0 + lr) * 16 + (lk << 2);
        b16x8 af = *(const b16x8*)&Bm[pia >> 6][68 + (pia & 63)];
        int pib = (j0 + lr) * 16 + (lk << 2);
        b16x8 bfr = *(const b16x8*)&Bm[32 + (pib >> 6)][68 + (pib & 63)];
        c = __builtin_amdgcn_mfma_f32_16x16x32_bf16(af, bfr, c, 0, 0, 0);
        #pragma unroll
        for (int q = 0; q < 4; ++q) Bm[crow + q][ccol] = c[q];
      }
      __syncthreads();
    }
  }

  // zero strict-upper of diag 16x16 blocks (8a/8b read full rows of them)
  for (int e = tid; e < 2048; e += 256){
    int b = e >> 8, r = (e >> 4) & 15, c = e & 15;
    if (c > r) Bm[(b << 4) + r][(b << 4) + c] = 0.0f;
  }

  // phase 8a: invert 16x16 unit-lower diag blocks in place.
  // Column-parallel forward substitution; waves 0-1, one block per 16-lane group.
  if (wv < 2){
    const int g = lane >> 4, c8 = lane & 15;
    const int ib = ((wv << 2) + g) << 4;
    float Lr[16], x[16];
    #pragma unroll
    for (int r = 0; r < 16; ++r){
      Lr[r] = Bm[ib + r][ib + c8];
      x[r] = (r == c8) ? 1.0f : 0.0f;
    }
    #pragma unroll
    for (int k = 0; k < 15; ++k){
      float xk = x[k];
      #pragma unroll
      for (int r = k + 1; r < 16; ++r){
        float lrk = __shfl(Lr[r], (lane & 48) | k);
        x[r] -= lrk * xk;
      }
    }
    #pragma unroll
    for (int r = 1; r < 16; ++r)
      if (r > c8) Bm[ib + r][ib + c8] = x[r];
  }
  __syncthreads();

  // phase 8b: off-diagonal blocks of S = L~^{-1}, in place
  {
    const int xr = lane >> 2;
    const int xc = (lane & 3) << 2;
    for (int I = 1; I < 8; ++I){
      __syncthreads();
      for (int J = wv; J < I; J += 4){
        int slot = J >> 2;
        f32x4 tv = (f32x4){0.f, 0.f, 0.f, 0.f};
        for (int K = J; K < I; ++K){
          #pragma unroll
          for (int kk = 0; kk < 16; ++kk){
            float l = Bm[(I << 4) + xr][(K << 4) + kk];
            f32x4 srow = *(f32x4*)&Bm[(K << 4) + kk][(J << 4) + xc];
            tv += l * srow;
          }
        }
        *(f32x4*)&Tscr[wv][slot][xr][xc] = tv;
      }
      __syncthreads();
      for (int J = wv; J < I; J += 4){
        int slot = J >> 2;
        f32x4 x = *(f32x4*)&Tscr[wv][slot][xr][xc];
        for (int k = 0; k < xr; ++k){
          float sik = Bm[(I << 4) + xr][(I << 4) + k];
          x += sik * (*(f32x4*)&Tscr[wv][slot][k][xc]);
        }
        *(f32x4*)&Bm[(I << 4) + xr][(J << 4) + xc] = -x;
      }
    }
  }
  __syncthreads();

  // phase 9a/9b: row sweeps: trace partials, p = S v~
  if (tid < 128){
    int i = tid;
    float asq = 0.f, ap = 0.f;
    for (int j4 = 0; j4 <= (i >> 2); ++j4){
      f32x4 v = *(f32x4*)&Bm[i][j4 << 2];
      f32x4 uv = *(f32x4*)&utlv[j4 << 2];
      #pragma unroll
      for (int q = 0; q < 4; ++q){
        int j = (j4 << 2) + q;
        bool ok = (j <= i);
        float sv = ok ? v[q] : 0.f;
        asq += sv * sv;
        ap  += sv * (ok ? uv[q] : 0.f);
      }
    }
    pvec[i] = ap;
    trv[i] = asq / dvec[i];
  }
  __syncthreads();
  if (tid < 128){
    utlv[tid] = pvec[tid] / dvec[tid];          // g = p / d
    epsv[tid] = epsv[tid] * rsqrtf(dvec[tid]);  // h = eps~ / sqrt(d)
  }
  __syncthreads();
  // phase 9c/9d: column sweeps: qmu~ = S^T g ; w~ = qmu~ + S^T h
  if (tid < 128){
    int j = tid;
    float aq = 0.f, aw = 0.f;
    for (int i = j; i < 128; ++i){
      float sij = Bm[i][j];
      aq += sij * utlv[i];
      aw += sij * epsv[i];
    }
    qmuv[j] = aq;
    wtv[j] = aq + aw;
  }
  __syncthreads();
  // phase 9e: reductions + kl; 9f: write w
  float ra = 0.f, rb = 0.f, rc = 0.f;
  if (tid < 128){
    ra = trv[tid];
    float q = qmuv[tid];
    rb = q * q;
    rc = logf(dvec[tid]);
  }
  #pragma unroll
  for (int off = 32; off > 0; off >>= 1){
    ra += __shfl_xor(ra, off);
    rb += __shfl_xor(rb, off);
    rc += __shfl_xor(rc, off);
  }
  if (lane == 0){
    red[wv * 4 + 0] = ra; red[wv * 4 + 1] = rb; red[wv * 4 + 2] = rc;
  }
  __syncthreads();
  if (tid == 0){
    float tr = red[0] + red[4] + red[8]  + red[12];
    float q2 = red[1] + red[5] + red[9]  + red[13];
    float ld = red[2] + red[6] + red[10] + red[14];
    klso[(s << 7) + o] = 0.5f * (tr + q2 - 128.0f + ld);
  }
  if (tid < 128)
    wout[(((size_t)(s << 7) + o) << 7) + tid] = wtv[127 - tid];
}

// ---------------- K3: F_out / U_out GEMMs ----------------
__global__ __launch_bounds__(256, 2) void k3_outs(
    const float* __restrict__ F, const float* __restrict__ U,
    const float* __restrict__ wbuf, float* __restrict__ out)
{
  __shared__ __align__(16) ushort Ab[128][136];
  __shared__ __align__(16) ushort Wb[128][136];
  const int tid = threadIdx.x;
  const int lane = tid & 63, wv = tid >> 6;
  const int bid = blockIdx.x;
  const float* src;
  float* dst;
  int s;
  if (bid < 512){
    s = bid >> 5;
    int t = bid & 31;
    size_t off = (((size_t)s * 4096) + (size_t)t * 128) * 128;
    src = F + off;
    dst = out + off;
  } else {
    s = bid - 512;
    src = U + ((size_t)s << 14);
    dst = out + (size_t)8388608 + ((size_t)s << 14);
  }
  for (int e = tid * 4; e < 16384; e += 1024){
    f32x4 v = *(const f32x4*)&src[e];
    uint p0 = (uint)f2bf(fmaxf(v[0], 0.f)) | ((uint)f2bf(fmaxf(v[1], 0.f)) << 16);
    uint p1 = (uint)f2bf(fmaxf(v[2], 0.f)) | ((uint)f2bf(fmaxf(v[3], 0.f)) << 16);
    uint2 pv; pv.x = p0; pv.y = p1;
    *(uint2*)&Ab[e >> 7][e & 127] = pv;
  }
  const float* wsrc = wbuf + ((size_t)s << 14);
  for (int e = tid * 4; e < 16384; e += 1024){
    f32x4 v = *(const f32x4*)&wsrc[e];
    uint p0 = (uint)f2bf(v[0]) | ((uint)f2bf(v[1]) << 16);
    uint p1 = (uint)f2bf(v[2]) | ((uint)f2bf(v[3]) << 16);
    uint2 pv; pv.x = p0; pv.y = p1;
    *(uint2*)&Wb[e >> 7][e & 127] = pv;
  }
  __syncthreads();
  f32x4 acc[2][8];
  mfma128(Ab, Wb, acc, wv, lane);
  const int lr = lane & 15, lk = lane >> 4;
  #pragma unroll
  for (int ti = 0; ti < 2; ++ti){
    #pragma unroll
    for (int tj = 0; tj < 8; ++tj){
      int c = tj * 16 + lr;
      #pragma unroll
      for (int q = 0; q < 4; ++q){
        int r = (wv * 2 + ti) * 16 + lk * 4 + q;
        dst[(size_t)r * 128 + c] = acc[ti][tj][q];
      }
    }
  }
}

// ---------------- K4: kl reduction ----------------
__global__ void k4_klred(const float* __restrict__ klso, float* __restrict__ klout){
  __shared__ float sums[16][17];
  const int t = threadIdx.x;
  int s = t >> 4, ch = t & 15;
  float a = 0.f;
  for (int q = 0; q < 8; ++q) a += klso[(s << 7) + ch * 8 + q];
  sums[s][ch] = a;
  __syncthreads();
  if (t < 16){
    float r = 0.f;
    for (int c = 0; c < 16; ++c) r += sums[t][c];
    klout[t] = r;
  }
}

extern "C" void kernel_launch(void* const* d_in, const int* in_sizes, int n_in,
                              void* d_out, int out_size, void* d_ws, size_t ws_size,
                              hipStream_t stream) {
  const float* F   = (const float*)d_in[0];
  const float* U   = (const float*)d_in[1];
  const float* mu  = (const float*)d_in[2];
  const float* lp  = (const float*)d_in[3];
  const float* eps = (const float*)d_in[4];
  float* out = (float*)d_out;
  char* ws = (char*)d_ws;
  ushort* phiUT = (ushort*)(ws + PHIUT_OFF);
  float* sqlp = (float*)(ws + SQLP_OFF);
  float* smu  = (float*)(ws + SMU_OFF);
  float* wbuf = (float*)(ws + WBUF_OFF);
  float* klso = (float*)(ws + KLSO_OFF);

  k0_prep<<<dim3(80), dim3(256), 0, stream>>>(U, mu, lp, phiUT, sqlp, smu);
  k2_factor<<<dim3(2048), dim3(256), 0, stream>>>(phiUT, sqlp, smu, eps, wbuf, klso);
  k3_outs<<<dim3(528), dim3(256), 0, stream>>>(F, U, wbuf, out);
  k4_klred<<<dim3(1), dim3(256), 0, stream>>>(klso, out + 8650752);
}